// Round 1
// baseline (66.135 us; speedup 1.0000x reference)
//
#include <hip/hip_runtime.h>
#include <cstddef>

#define NUM_TYPE 64
#define DD 256          // D_IN == D_OUT
#define NN 8192
#define TM 64           // rows per tile
#define BK 32           // K chunk
#define LSTRIDE (BK + 8) // LDS row stride in bf16 elems (pad kills bank conflicts)
#define YT 2            // row-tile blocks per type

typedef __bf16 bf16x8 __attribute__((ext_vector_type(8)));
typedef float f32x4 __attribute__((ext_vector_type(4)));

__device__ __forceinline__ unsigned short f2bf(float f) {
  unsigned int u = __builtin_bit_cast(unsigned int, f);
  u += 0x7FFFu + ((u >> 16) & 1u);   // round-to-nearest-even
  return (unsigned short)(u >> 16);
}

// --- Kernel 1: group samples by type ------------------------------------
__global__ void build_perm_kernel(const int* __restrict__ bi,
                                  int* __restrict__ type_off,
                                  int* __restrict__ perm) {
  __shared__ int cnt[NUM_TYPE];
  __shared__ int base[NUM_TYPE];
  const int tid = threadIdx.x;
  if (tid < NUM_TYPE) cnt[tid] = 0;
  __syncthreads();
  for (int i = tid; i < NN; i += blockDim.x) atomicAdd(&cnt[bi[i]], 1);
  __syncthreads();
  if (tid == 0) {
    int s = 0;
    for (int t = 0; t < NUM_TYPE; ++t) { base[t] = s; type_off[t] = s; s += cnt[t]; }
    type_off[NUM_TYPE] = s;
  }
  __syncthreads();
  for (int i = tid; i < NN; i += blockDim.x) {
    int p = atomicAdd(&base[bi[i]], 1);
    perm[p] = i;
  }
}

// --- Kernel 2: per-type fused GEMM: out = tanh(D@L^T) + D@W^T + b -------
__global__ __launch_bounds__(512, 1) void fused_kernel(
    const float* __restrict__ desc,    // [NN][DD]
    const float* __restrict__ layer1,  // [NUM_TYPE][DD][DD]
    const float* __restrict__ W,       // [DD][DD]
    const float* __restrict__ bias,    // [DD]
    const int* __restrict__ type_off,  // [NUM_TYPE+1]
    const int* __restrict__ perm,      // [NN]
    float* __restrict__ out) {         // [NN][DD]
  const int t = blockIdx.x;
  const int yt = blockIdx.y;
  const int off = type_off[t];
  const int cnt = type_off[t + 1] - off;
  if (cnt <= 0) return;

  __shared__ unsigned short Abuf[TM * LSTRIDE];        // 5 KB
  __shared__ unsigned short Bbuf[2 * DD * LSTRIDE];    // 40 KB (L rows 0..255, W rows 256..511)
  __shared__ int permTile[TM];

  const int tid = threadIdx.x;
  const int wave = tid >> 6;      // 0..7, owns output cols [32w, 32w+32)
  const int lane = tid & 63;
  const int l15 = lane & 15;
  const int lg = lane >> 4;       // 0..3

  const int arow = tid >> 3;      // 0..63 (staging row)
  const int aseg = tid & 7;       // 0..7  (staging float4 segment)

  for (int mt = yt; mt * TM < cnt; mt += YT) {
    __syncthreads();              // prev iter's epilogue done before permTile rewrite
    if (tid < TM) {
      int r = mt * TM + tid;
      permTile[tid] = (r < cnt) ? perm[off + r] : -1;
    }

    f32x4 accL[4][2], accW[4][2];
#pragma unroll
    for (int m = 0; m < 4; ++m)
#pragma unroll
      for (int n = 0; n < 2; ++n) { accL[m][n] = {}; accW[m][n] = {}; }

    for (int kc = 0; kc < DD / BK; ++kc) {
      const int kb = kc * BK;
      __syncthreads();
      // stage A: 64 rows x 32 k (gathered descriptor rows), fp32 -> bf16
      {
        int s = permTile[arow];
        float4 v = make_float4(0.f, 0.f, 0.f, 0.f);
        if (s >= 0) v = *reinterpret_cast<const float4*>(&desc[(size_t)s * DD + kb + aseg * 4]);
        ushort4 h;
        h.x = f2bf(v.x); h.y = f2bf(v.y); h.z = f2bf(v.z); h.w = f2bf(v.w);
        *reinterpret_cast<ushort4*>(&Abuf[arow * LSTRIDE + aseg * 4]) = h;
      }
      // stage B: 512 rows x 32 k (layer1[t] then W), fp32 -> bf16
#pragma unroll
      for (int p = 0; p < 8; ++p) {
        int row = arow + p * 64;
        const float* src = (row < DD)
            ? &layer1[((size_t)t * DD + row) * DD + kb + aseg * 4]
            : &W[(size_t)(row - DD) * DD + kb + aseg * 4];
        float4 v = *reinterpret_cast<const float4*>(src);
        ushort4 h;
        h.x = f2bf(v.x); h.y = f2bf(v.y); h.z = f2bf(v.z); h.w = f2bf(v.w);
        *reinterpret_cast<ushort4*>(&Bbuf[row * LSTRIDE + aseg * 4]) = h;
      }
      __syncthreads();
      // compute: wave handles 64 rows x 32 cols of L and the same 32 cols of W
      bf16x8 af[4];
#pragma unroll
      for (int m = 0; m < 4; ++m)
        af[m] = *reinterpret_cast<const bf16x8*>(&Abuf[(m * 16 + l15) * LSTRIDE + lg * 8]);
#pragma unroll
      for (int n = 0; n < 2; ++n) {
        const int rn = wave * 32 + n * 16 + l15;
        bf16x8 bL = *reinterpret_cast<const bf16x8*>(&Bbuf[rn * LSTRIDE + lg * 8]);
        bf16x8 bW = *reinterpret_cast<const bf16x8*>(&Bbuf[(DD + rn) * LSTRIDE + lg * 8]);
#pragma unroll
        for (int m = 0; m < 4; ++m) {
          accL[m][n] = __builtin_amdgcn_mfma_f32_16x16x32_bf16(af[m], bL, accL[m][n], 0, 0, 0);
          accW[m][n] = __builtin_amdgcn_mfma_f32_16x16x32_bf16(af[m], bW, accW[m][n], 0, 0, 0);
        }
      }
    }
    // epilogue: out[s][col] = tanh(accL) + accW + b[col], scattered by perm
#pragma unroll
    for (int n = 0; n < 2; ++n) {
      const int col = wave * 32 + n * 16 + l15;
      const float bv = bias[col];
#pragma unroll
      for (int m = 0; m < 4; ++m) {
#pragma unroll
        for (int r = 0; r < 4; ++r) {
          int rowT = m * 16 + lg * 4 + r;
          int s = permTile[rowT];
          if (s >= 0) out[(size_t)s * DD + col] = tanhf(accL[m][n][r]) + accW[m][n][r] + bv;
        }
      }
    }
  }
}

extern "C" void kernel_launch(void* const* d_in, const int* in_sizes, int n_in,
                              void* d_out, int out_size, void* d_ws, size_t ws_size,
                              hipStream_t stream) {
  const int* bi      = (const int*)d_in[0];
  const float* desc  = (const float*)d_in[1];
  const float* layer1= (const float*)d_in[2];
  const float* W     = (const float*)d_in[3];
  const float* bias  = (const float*)d_in[4];
  float* out = (float*)d_out;

  int* wsI = (int*)d_ws;
  int* type_off = wsI;        // 65 ints
  int* perm     = wsI + 72;   // 8192 ints

  hipLaunchKernelGGL(build_perm_kernel, dim3(1), dim3(256), 0, stream, bi, type_off, perm);
  hipLaunchKernelGGL(fused_kernel, dim3(NUM_TYPE, YT), dim3(512), 0, stream,
                     desc, layer1, W, bias, type_off, perm, out);
}

// Round 2
// 49.899 us; speedup vs baseline: 1.3254x; 1.3254x over previous
//
#include <hip/hip_runtime.h>
#include <cstddef>

#define NUM_TYPE 64
#define DD 256
#define NN 8192

typedef __bf16 bf16x8 __attribute__((ext_vector_type(8)));
typedef float f32x4 __attribute__((ext_vector_type(4)));

// --- Kernel 1: group samples by type (1024 thr, per-wave histograms) -----
__global__ __launch_bounds__(1024) void build_perm_kernel(
    const int* __restrict__ bi, int* __restrict__ type_off, int* __restrict__ perm) {
  __shared__ int wcnt[16][NUM_TYPE];
  __shared__ int wbase[16][NUM_TYPE];
  __shared__ int base[NUM_TYPE];
  const int tid = threadIdx.x;
  const int w = tid >> 6;
  for (int i = tid; i < 16 * NUM_TYPE; i += 1024) ((int*)wcnt)[i] = 0;
  __syncthreads();
  int myv[8];
#pragma unroll
  for (int rnd = 0; rnd < 8; ++rnd) {
    int v = bi[rnd * 1024 + tid];
    myv[rnd] = v;
    atomicAdd(&wcnt[w][v], 1);
  }
  __syncthreads();
  if (tid < NUM_TYPE) {
    int s = 0;
#pragma unroll
    for (int ww = 0; ww < 16; ++ww) { wbase[ww][tid] = s; s += wcnt[ww][tid]; }
    base[tid] = s;                       // per-type total
  }
  __syncthreads();
  if (tid == 0) {
    int s = 0;
    for (int t = 0; t < NUM_TYPE; ++t) { int c = base[t]; base[t] = s; type_off[t] = s; s += c; }
    type_off[NUM_TYPE] = s;
  }
  __syncthreads();
  if (tid < NUM_TYPE) {
    int b = base[tid];
#pragma unroll
    for (int ww = 0; ww < 16; ++ww) wbase[ww][tid] += b;
  }
  __syncthreads();
#pragma unroll
  for (int rnd = 0; rnd < 8; ++rnd) {
    int v = myv[rnd];
    int p = atomicAdd(&wbase[w][v], 1);  // intra-wave collisions only
    perm[p] = rnd * 1024 + tid;
  }
}

// --- helpers -------------------------------------------------------------
__device__ __forceinline__ bf16x8 cvt8(const float* p) {
  float4 v0 = *reinterpret_cast<const float4*>(p);
  float4 v1 = *reinterpret_cast<const float4*>(p + 4);
  bf16x8 h;
  h[0] = (__bf16)v0.x; h[1] = (__bf16)v0.y; h[2] = (__bf16)v0.z; h[3] = (__bf16)v0.w;
  h[4] = (__bf16)v1.x; h[5] = (__bf16)v1.y; h[6] = (__bf16)v1.z; h[7] = (__bf16)v1.w;
  return h;
}

__device__ __forceinline__ float tanh_fast(float x) {
  float xc = fminf(fmaxf(x, -15.f), 15.f);
  float e = __expf(2.f * xc);            // v_exp_f32 path
  return (e - 1.f) / (e + 1.f);
}

// --- Kernel 2: per-wave 32x32 register tile, no LDS, no barriers ---------
// out[s][c] = tanh(desc[s]·L[t][c]) + desc[s]·W[c] + b[c]
__global__ __launch_bounds__(256) void fused_kernel(
    const float* __restrict__ desc,    // [NN][DD]
    const float* __restrict__ layer1,  // [NUM_TYPE][DD][DD]
    const float* __restrict__ W,       // [DD][DD]
    const float* __restrict__ bias,    // [DD]
    const int* __restrict__ type_off,  // [NUM_TYPE+1]
    const int* __restrict__ perm,      // [NN]
    float* __restrict__ out) {         // [NN][DD]
  const int t = blockIdx.y;
  const int off = type_off[t];
  const int cnt = type_off[t + 1] - off;
  const int wave = threadIdx.x >> 6;
  const int lane = threadIdx.x & 63;
  const int l15 = lane & 15;
  const int lg = lane >> 4;

  const int colbase = blockIdx.x * 128 + wave * 32;
  const int cn0 = colbase + l15;
  const int cn1 = cn0 + 16;

  // per-lane B row pointers, pre-offset by lg*8 (k sub-chunk)
  const float* bl0 = layer1 + ((size_t)t * DD + cn0) * DD + lg * 8;
  const float* bl1 = layer1 + ((size_t)t * DD + cn1) * DD + lg * 8;
  const float* bw0 = W + (size_t)cn0 * DD + lg * 8;
  const float* bw1 = W + (size_t)cn1 * DD + lg * 8;
  const float bv0 = bias[cn0];
  const float bv1 = bias[cn1];

  for (int mt = blockIdx.z; mt * 32 < cnt; mt += 4) {
    const int rbase = mt * 32;
    const int r0 = rbase + l15;
    const int r1 = r0 + 16;
    const int s0 = (r0 < cnt) ? perm[off + r0] : -1;
    const int s1 = (r1 < cnt) ? perm[off + r1] : -1;
    const float* a0 = desc + (size_t)(s0 < 0 ? 0 : s0) * DD + lg * 8;
    const float* a1 = desc + (size_t)(s1 < 0 ? 0 : s1) * DD + lg * 8;

    f32x4 accL[2][2] = {{{0.f,0.f,0.f,0.f},{0.f,0.f,0.f,0.f}},
                        {{0.f,0.f,0.f,0.f},{0.f,0.f,0.f,0.f}}};
    f32x4 accW[2][2] = {{{0.f,0.f,0.f,0.f},{0.f,0.f,0.f,0.f}},
                        {{0.f,0.f,0.f,0.f},{0.f,0.f,0.f,0.f}}};

#pragma unroll 2
    for (int kc = 0; kc < 8; ++kc) {
      const int ko = kc * 32;
      bf16x8 af0 = cvt8(a0 + ko);
      bf16x8 af1 = cvt8(a1 + ko);
      bf16x8 bL0 = cvt8(bl0 + ko);
      bf16x8 bL1 = cvt8(bl1 + ko);
      bf16x8 bW0 = cvt8(bw0 + ko);
      bf16x8 bW1 = cvt8(bw1 + ko);
      accL[0][0] = __builtin_amdgcn_mfma_f32_16x16x32_bf16(af0, bL0, accL[0][0], 0, 0, 0);
      accL[0][1] = __builtin_amdgcn_mfma_f32_16x16x32_bf16(af0, bL1, accL[0][1], 0, 0, 0);
      accL[1][0] = __builtin_amdgcn_mfma_f32_16x16x32_bf16(af1, bL0, accL[1][0], 0, 0, 0);
      accL[1][1] = __builtin_amdgcn_mfma_f32_16x16x32_bf16(af1, bL1, accL[1][1], 0, 0, 0);
      accW[0][0] = __builtin_amdgcn_mfma_f32_16x16x32_bf16(af0, bW0, accW[0][0], 0, 0, 0);
      accW[0][1] = __builtin_amdgcn_mfma_f32_16x16x32_bf16(af0, bW1, accW[0][1], 0, 0, 0);
      accW[1][0] = __builtin_amdgcn_mfma_f32_16x16x32_bf16(af1, bW0, accW[1][0], 0, 0, 0);
      accW[1][1] = __builtin_amdgcn_mfma_f32_16x16x32_bf16(af1, bW1, accW[1][1], 0, 0, 0);
    }

    // epilogue: C layout row = lg*4 + i (within 16), col = l15
#pragma unroll
    for (int m = 0; m < 2; ++m) {
      const int sFrag = m ? s1 : s0;   // lane l15 holds perm for row l15 of frag m
#pragma unroll
      for (int i = 0; i < 4; ++i) {
        const int sv = __shfl(sFrag, lg * 4 + i, 64);
        if (sv >= 0) {
          float* op = out + (size_t)sv * DD;
          op[cn0] = tanh_fast(accL[m][0][i]) + accW[m][0][i] + bv0;
          op[cn1] = tanh_fast(accL[m][1][i]) + accW[m][1][i] + bv1;
        }
      }
    }
  }
}

extern "C" void kernel_launch(void* const* d_in, const int* in_sizes, int n_in,
                              void* d_out, int out_size, void* d_ws, size_t ws_size,
                              hipStream_t stream) {
  const int* bi       = (const int*)d_in[0];
  const float* desc   = (const float*)d_in[1];
  const float* layer1 = (const float*)d_in[2];
  const float* W      = (const float*)d_in[3];
  const float* bias   = (const float*)d_in[4];
  float* out = (float*)d_out;

  int* wsI = (int*)d_ws;
  int* type_off = wsI;        // 65 ints
  int* perm     = wsI + 72;   // 8192 ints

  hipLaunchKernelGGL(build_perm_kernel, dim3(1), dim3(1024), 0, stream, bi, type_off, perm);
  hipLaunchKernelGGL(fused_kernel, dim3(2, NUM_TYPE, 4), dim3(256), 0, stream,
                     desc, layer1, W, bias, type_off, perm, out);
}